// Round 8
// baseline (10952.280 us; speedup 1.0000x reference)
//
#include <hip/hip_runtime.h>
#include <math.h>

typedef _Float16 f16;
typedef _Float16 f16x8 __attribute__((ext_vector_type(8)));
typedef _Float16 f16x4 __attribute__((ext_vector_type(4)));
typedef _Float16 f16x2 __attribute__((ext_vector_type(2)));
typedef float f32x4 __attribute__((ext_vector_type(4)));
typedef int i32x4 __attribute__((ext_vector_type(4)));

#define B_ 32
#define T_ 1024
#define I_ 128
#define H_ 512

#define NWG 32
#define THR 512

// ---- workspace layout (bytes) ----
// Data arrays: write-once slots, slot k = h[t=k-1]; slot = [wg 0..31][1KB block].
// Trailer arrays: per (slot, wg) 16B {epoch, ck0, ck1, 0}.
#define OFF_TR1   0UL                 // [1025][512] = 524,800 (reserve 525,312)
#define OFF_TR2   525312UL            // same
#define OFF_H1S   1050624UL           // 1025*32768 = 33,587,200
#define OFF_H2S   34637824UL          // 33,587,200
#define OFF_XT    68225024UL          // f16 [1024][32][128] = 8,388,608
// total 76,613,632 B

__device__ inline f32x4 mfma16(f16x8 a, f16x8 b, f32x4 c) {
  return __builtin_amdgcn_mfma_f32_16x16x32_f16(a, b, c, 0, 0, 0);
}
__device__ inline float fast_sig(float x) { return 1.f / (1.f + __expf(-x)); }
__device__ inline float fast_tanh(float x) {
  float e = __expf(-2.f * fabsf(x));
  float t = (1.f - e) / (1.f + e);
  return x < 0.f ? -t : t;
}
__device__ inline unsigned rotl32(unsigned d, unsigned r) {
  return (d << r) | (d >> ((32u - r) & 31u));
}

// sc1 = device-coherent (MALL) ops
__device__ inline void st_sc1_u32(unsigned* p, unsigned v) {
  asm volatile("global_store_dword %0, %1, off sc1" :: "v"(p), "v"(v) : "memory");
}
__device__ inline void st_sc1_b128(void* p, i32x4 v) {
  asm volatile("global_store_dwordx4 %0, %1, off sc1" :: "v"(p), "v"(v) : "memory");
}
__device__ inline i32x4 ld_sc1_b128_async(const void* p) {  // no wait; wait_vm0 before use
  i32x4 r;
  asm volatile("global_load_dwordx4 %0, %1, off sc1" : "=&v"(r) : "v"(p) : "memory");
  return r;
}
__device__ inline void wait_vm0() {
  asm volatile("s_waitcnt vmcnt(0)" ::: "memory");
  __builtin_amdgcn_sched_barrier(0);
}

// wave-uniform verdict over this wave's 4 blocks (block br = r*8+wv; chunk = lane)
__device__ inline bool verify4(const i32x4* d, const i32x4* t, int lane, int epoch) {
  bool ok = true;
#pragma unroll
  for (int r = 0; r < 4; ++r) {
    unsigned p0 = (unsigned)d[r].x ^ (unsigned)d[r].y ^ (unsigned)d[r].z ^ (unsigned)d[r].w;
    const unsigned base = (unsigned)(4 * lane) & 31u;
    unsigned p1 = rotl32((unsigned)d[r].x, base) ^ rotl32((unsigned)d[r].y, base + 1) ^
                  rotl32((unsigned)d[r].z, base + 2) ^ rotl32((unsigned)d[r].w, base + 3);
#pragma unroll
    for (int m = 1; m < 64; m <<= 1) {
      p0 ^= (unsigned)__shfl_xor((int)p0, m, 64);
      p1 ^= (unsigned)__shfl_xor((int)p1, m, 64);
    }
    ok &= ((unsigned)t[r].x == (unsigned)epoch) &
          ((unsigned)t[r].y == p0) & ((unsigned)t[r].z == p1);
  }
  return ok;
}

// LDS XOR-swizzle (R2/R6-proven)
__device__ inline int swz_h(int b, int kbyte) { return b * 1024 + (kbyte ^ ((b & 7) << 4)); }
__device__ inline int swz_x(int b, int kbyte) { return b * 256  + (kbyte ^ ((b & 7) << 4)); }

// x[b][t][i] f32 -> xT[t][b][i] f16
__global__ __launch_bounds__(256) void prep_xT(const float* __restrict__ x, f16* __restrict__ xT) {
  const int idx = blockIdx.x * 256 + threadIdx.x;
  const int n4 = B_ * T_ * I_ / 4;
  if (idx < n4) {
    const int i4 = idx * 4;
    const int i  = i4 & (I_ - 1);
    const int tt = (i4 >> 7) & (T_ - 1);
    const int b  = i4 >> 17;
    float4 v = *(const float4*)(x + i4);
    f16x4 o;
    o[0] = (f16)v.x; o[1] = (f16)v.y; o[2] = (f16)v.z; o[3] = (f16)v.w;
    *(f16x4*)(xT + ((size_t)tt * B_ + b) * I_ + i) = o;
  }
}

// Persistent merged 2-layer LSTM; checksum-verified speculative exchange (no barrier/flags).
__global__ __launch_bounds__(THR, 1) void lstm_persist(
    const float* __restrict__ Wih0, const float* __restrict__ Whh0,
    const float* __restrict__ bih0, const float* __restrict__ bhh0,
    const float* __restrict__ Wih1, const float* __restrict__ Whh1,
    const float* __restrict__ bih1, const float* __restrict__ bhh1,
    char* ws) {
  __shared__ i32x4 h1l4[2048];         // 32KB  h1[s-1] (swizzled)
  __shared__ i32x4 h2l4[2048];         // 32KB  h2[s-2] (swizzled)
  __shared__ i32x4 xl4[512];           // 8KB   x[s] (swizzled)
  __shared__ float g0[2 * 32 * 68];    // gate partials
  __shared__ float g1[2 * 32 * 68];
  __shared__ float bias0[64], bias1[64];
  __shared__ unsigned cks[512];        // checksum scratch
  __shared__ int vbuf[16];             // per-wave verdicts

  const int tid  = threadIdx.x;
  const int wg   = blockIdx.x;
  const int lane = tid & 63;
  const int wv   = tid >> 6;
  const int nt   = wv & 3;
  const int kh   = wv >> 2;
  const int cfr  = lane & 15;
  const int ksub = lane >> 4;

  const char* h1base = ws + OFF_H1S;
  const char* h2base = ws + OFF_H2S;
  char* tr1 = ws + OFF_TR1;
  char* tr2 = ws + OFF_TR2;

  if (tid < 64) {
    const int g = tid >> 4, hc = tid & 15;
    const int row = g * 512 + wg * 16 + hc;
    bias0[tid] = bih0[row] + bhh0[row];
    bias1[tid] = bih1[row] + bhh1[row];
  }

  // ---- weight preload into VGPRs (R2-identical) ----
  const int gc  = nt * 16 + cfr;
  const int row = (gc >> 4) * 512 + wg * 16 + (gc & 15);
  f16x8 wa[10];
#pragma unroll
  for (int ksl = 0; ksl < 10; ++ksl) {
    const int k = (kh * 10 + ksl) * 32 + ksub * 8;
    const float* src = (k < I_) ? (Wih0 + (size_t)row * I_ + k)
                                : (Whh0 + (size_t)row * H_ + (k - I_));
    float4 v0 = *(const float4*)(src);
    float4 v1 = *(const float4*)(src + 4);
    f16x8 h;
    h[0] = (f16)v0.x; h[1] = (f16)v0.y; h[2] = (f16)v0.z; h[3] = (f16)v0.w;
    h[4] = (f16)v1.x; h[5] = (f16)v1.y; h[6] = (f16)v1.z; h[7] = (f16)v1.w;
    wa[ksl] = h;
  }
  f16x8 wb[16];
#pragma unroll
  for (int ksl = 0; ksl < 16; ++ksl) {
    const int k = (kh * 16 + ksl) * 32 + ksub * 8;
    const float* src = (k < H_) ? (Wih1 + (size_t)row * H_ + k)
                                : (Whh1 + (size_t)row * H_ + (k - H_));
    float4 v0 = *(const float4*)(src);
    float4 v1 = *(const float4*)(src + 4);
    f16x8 h;
    h[0] = (f16)v0.x; h[1] = (f16)v0.y; h[2] = (f16)v0.z; h[3] = (f16)v0.w;
    h[4] = (f16)v1.x; h[5] = (f16)v1.y; h[6] = (f16)v1.z; h[7] = (f16)v1.w;
    wb[ksl] = h;
  }

  float cst0 = 0.f, cst1 = 0.f;        // L0 cell state (threads 0..255)
  float dst0 = 0.f, dst1 = 0.f;        // L1 cell state (threads 256..511)
  const char* h1c = (const char*)h1l4;
  const char* h2c = (const char*)h2l4;
  const char* xc  = (const char*)xl4;

  __syncthreads();

  for (int s = 0; s <= T_; ++s) {
    const bool hasx = (s < T_);
    i32x4 xv;
    if (hasx) xv = ((const i32x4*)(ws + OFF_XT))[(size_t)s * 512 + tid];

    // ---- speculative verified gather: h1 slot s (epoch s), h2 slot s-1 (epoch s-1) ----
    i32x4 d1[4], t1[4], d2[4], t2[4];
    const bool v1 = (s >= 1);          // slot 0 = memset zeros, no verify
    const bool v2 = (s >= 2);
    bool ok1 = false, ok2 = (s >= 1) ? false : true;
    int att = 0;
    for (;;) {
      if (!ok1) {
        const char* src = h1base + (size_t)s * 32768;
#pragma unroll
        for (int r = 0; r < 4; ++r)
          d1[r] = ld_sc1_b128_async(src + (r * 512 + tid) * 16);
#pragma unroll
        for (int r = 0; r < 4; ++r)
          t1[r] = ld_sc1_b128_async(tr1 + (size_t)s * 512 + (r * 8 + wv) * 16);
      }
      if (!ok2) {
        const char* src = h2base + (size_t)(s - 1) * 32768;
#pragma unroll
        for (int r = 0; r < 4; ++r)
          d2[r] = ld_sc1_b128_async(src + (r * 512 + tid) * 16);
#pragma unroll
        for (int r = 0; r < 4; ++r)
          t2[r] = ld_sc1_b128_async(tr2 + (size_t)(s - 1) * 512 + (r * 8 + wv) * 16);
      }
      wait_vm0();
      const bool m1 = ok1 || !v1 || verify4(d1, t1, lane, s);
      const bool m2 = ok2 || !v2 || verify4(d2, t2, lane, s - 1);
      if (lane == 0) { vbuf[wv] = m1 ? 1 : 0; vbuf[8 + wv] = m2 ? 1 : 0; }
      __syncthreads();
      int a1 = 1, a2 = 1;
#pragma unroll
      for (int w = 0; w < 8; ++w) { a1 &= vbuf[w]; a2 &= vbuf[8 + w]; }
      __syncthreads();
      ok1 = ok1 || (a1 != 0);
      ok2 = ok2 || (a2 != 0);
      if (ok1 && ok2) break;
      if (++att > 512) break;          // dead-latch: fast visible failure, never a hang
    }

    // ---- stage accepted registers -> swizzled LDS ----
#pragma unroll
    for (int r = 0; r < 4; ++r) {
      const int u = r * 512 + tid;
      const int wgs = u >> 6, b = (u >> 1) & 31, half = u & 1;
      *(i32x4*)((char*)h1l4 + swz_h(b, wgs * 32 + half * 16)) = d1[r];
    }
    if (s >= 1) {
#pragma unroll
      for (int r = 0; r < 4; ++r) {
        const int u = r * 512 + tid;
        const int wgs = u >> 6, b = (u >> 1) & 31, half = u & 1;
        *(i32x4*)((char*)h2l4 + swz_h(b, wgs * 32 + half * 16)) = d2[r];
      }
    }
    if (hasx) *(i32x4*)((char*)xl4 + swz_x(tid >> 4, (tid & 15) * 16)) = xv;
    __syncthreads();

    // ---- MFMA phase (R6-identical) ----
    if (s < T_) {
      f32x4 a0 = {0.f, 0.f, 0.f, 0.f}, a1 = {0.f, 0.f, 0.f, 0.f};
#pragma unroll
      for (int ksl = 0; ksl < 10; ++ksl) {
        const int k = (kh * 10 + ksl) * 32 + ksub * 8;
        f16x8 af0, af1;
        if (k < I_) {
          af0 = *(const f16x8*)(xc + swz_x(cfr,      k * 2));
          af1 = *(const f16x8*)(xc + swz_x(16 + cfr, k * 2));
        } else {
          af0 = *(const f16x8*)(h1c + swz_h(cfr,      (k - I_) * 2));
          af1 = *(const f16x8*)(h1c + swz_h(16 + cfr, (k - I_) * 2));
        }
        a0 = mfma16(af0, wa[ksl], a0);
        a1 = mfma16(af1, wa[ksl], a1);
      }
      const int base = kh * 2176 + (ksub * 4) * 68 + nt * 16 + cfr;
#pragma unroll
      for (int r = 0; r < 4; ++r) {
        g0[base + r * 68]           = a0[r];
        g0[base + 16 * 68 + r * 68] = a1[r];
      }
    }
    if (s >= 1) {
      f32x4 a0 = {0.f, 0.f, 0.f, 0.f}, a1 = {0.f, 0.f, 0.f, 0.f};
#pragma unroll
      for (int ksl = 0; ksl < 16; ++ksl) {
        const int k = (kh * 16 + ksl) * 32 + ksub * 8;
        f16x8 af0, af1;
        if (k < H_) {
          af0 = *(const f16x8*)(h1c + swz_h(cfr,      k * 2));
          af1 = *(const f16x8*)(h1c + swz_h(16 + cfr, k * 2));
        } else {
          af0 = *(const f16x8*)(h2c + swz_h(cfr,      (k - H_) * 2));
          af1 = *(const f16x8*)(h2c + swz_h(16 + cfr, (k - H_) * 2));
        }
        a0 = mfma16(af0, wb[ksl], a0);
        a1 = mfma16(af1, wb[ksl], a1);
      }
      const int base = kh * 2176 + (ksub * 4) * 68 + nt * 16 + cfr;
#pragma unroll
      for (int r = 0; r < 4; ++r) {
        g1[base + r * 68]           = a0[r];
        g1[base + 16 * 68 + r * 68] = a1[r];
      }
    }
    __syncthreads();

    // ---- pointwise + fire-and-forget data stores + checksum scratch ----
    if (s < T_ && tid < 256) {         // L0 -> H1S slot s+1
      const int rb = tid >> 3, hp = tid & 7;
      const float* gr = g0 + rb * 68;
      float hv[2];
#pragma unroll
      for (int cc = 0; cc < 2; ++cc) {
        const int c = 2 * hp + cc;
        const float pi = gr[c]      + gr[2176 + c]      + bias0[c];
        const float pf = gr[16 + c] + gr[2176 + 16 + c] + bias0[16 + c];
        const float pg = gr[32 + c] + gr[2176 + 32 + c] + bias0[32 + c];
        const float po = gr[48 + c] + gr[2176 + 48 + c] + bias0[48 + c];
        const float ig = fast_sig(pi), fg = fast_sig(pf);
        const float gg = fast_tanh(pg), og = fast_sig(po);
        const float cprev = cc ? cst1 : cst0;
        const float cnew = fg * cprev + ig * gg;
        if (cc) cst1 = cnew; else cst0 = cnew;
        hv[cc] = og * fast_tanh(cnew);
      }
      f16x2 pk; pk[0] = (f16)hv[0]; pk[1] = (f16)hv[1];
      const unsigned dw = __builtin_bit_cast(unsigned, pk);
      st_sc1_u32((unsigned*)(h1base + (size_t)(s + 1) * 32768 +
                             (size_t)wg * 1024 + rb * 32 + hp * 4), dw);
      cks[tid] = dw;                   // dword index i == tid
    }
    if (s >= 1 && tid >= 256) {        // L1 -> H2S slot s
      const int t2i = tid - 256;
      const int rb = t2i >> 3, hp = t2i & 7;
      const float* gr = g1 + rb * 68;
      float hv[2];
#pragma unroll
      for (int cc = 0; cc < 2; ++cc) {
        const int c = 2 * hp + cc;
        const float pi = gr[c]      + gr[2176 + c]      + bias1[c];
        const float pf = gr[16 + c] + gr[2176 + 16 + c] + bias1[16 + c];
        const float pg = gr[32 + c] + gr[2176 + 32 + c] + bias1[32 + c];
        const float po = gr[48 + c] + gr[2176 + 48 + c] + bias1[48 + c];
        const float ig = fast_sig(pi), fg = fast_sig(pf);
        const float gg = fast_tanh(pg), og = fast_sig(po);
        const float cprev = cc ? dst1 : dst0;
        const float cnew = fg * cprev + ig * gg;
        if (cc) dst1 = cnew; else dst0 = cnew;
        hv[cc] = og * fast_tanh(cnew);
      }
      f16x2 pk; pk[0] = (f16)hv[0]; pk[1] = (f16)hv[1];
      const unsigned dw = __builtin_bit_cast(unsigned, pk);
      st_sc1_u32((unsigned*)(h2base + (size_t)s * 32768 +
                             (size_t)wg * 1024 + rb * 32 + hp * 4), dw);
      cks[tid] = dw;
    }
    __syncthreads();

    // ---- trailer: per-layer checksum reduce (one wave each) + sc1 store ----
    if (s < T_ && wv == 0) {
      unsigned q0 = cks[lane] ^ cks[64 + lane] ^ cks[128 + lane] ^ cks[192 + lane];
      unsigned q1 = rotl32(q0, (unsigned)lane & 31u);
#pragma unroll
      for (int m = 1; m < 64; m <<= 1) {
        q0 ^= (unsigned)__shfl_xor((int)q0, m, 64);
        q1 ^= (unsigned)__shfl_xor((int)q1, m, 64);
      }
      if (lane == 0) {
        i32x4 tr; tr.x = s + 1; tr.y = (int)q0; tr.z = (int)q1; tr.w = 0;
        st_sc1_b128(tr1 + (size_t)(s + 1) * 512 + wg * 16, tr);
      }
    }
    if (s >= 1 && wv == 4) {
      unsigned q0 = cks[256 + lane] ^ cks[320 + lane] ^ cks[384 + lane] ^ cks[448 + lane];
      unsigned q1 = rotl32(q0, (unsigned)lane & 31u);
#pragma unroll
      for (int m = 1; m < 64; m <<= 1) {
        q0 ^= (unsigned)__shfl_xor((int)q0, m, 64);
        q1 ^= (unsigned)__shfl_xor((int)q1, m, 64);
      }
      if (lane == 0) {
        i32x4 tr; tr.x = s; tr.y = (int)q0; tr.z = (int)q1; tr.w = 0;
        st_sc1_b128(tr2 + (size_t)s * 512 + wg * 16, tr);
      }
    }
    // next iteration's gather vmcnt(0) doubles as the store drain; no barrier needed here
  }
}

// fused FC1+FC2 reading block layout (R6-identical): rows bt = b*1024 + t.
__global__ __launch_bounds__(256) void fc_fused(const char* __restrict__ ws_h2,
                                                const float* __restrict__ fcW,
                                                const float* __restrict__ fcb,
                                                const float* __restrict__ fc2W,
                                                const float* __restrict__ fc2b,
                                                float* __restrict__ out) {
  __shared__ float hT[64][36];
  __shared__ float wT[128][36];
  __shared__ float oL[64][136];
  const int bt0 = blockIdx.x * 64;
  const int b   = bt0 >> 10;
  const int t0  = bt0 & 1023;
  const int t = threadIdx.x;
  const int c4 = (t & 31) * 4;
  const int rowg = t >> 5;
  float acc[8][4];
#pragma unroll
  for (int r = 0; r < 8; ++r)
#pragma unroll
    for (int j = 0; j < 4; ++j) acc[r][j] = 0.f;

  for (int kc = 0; kc < 16; ++kc) {
    {
      const int r = t >> 2, q = t & 3;
      const int c0 = kc * 32 + q * 8;
      const f16x8 v = *(const f16x8*)(ws_h2 + (size_t)(t0 + r + 1) * 32768 +
                                      (size_t)(c0 >> 4) * 1024 + b * 32 + (c0 & 15) * 2);
#pragma unroll
      for (int j = 0; j < 8; ++j) hT[r][q * 8 + j] = (float)v[j];
    }
#pragma unroll
    for (int u = t; u < 1024; u += 256) {
      const int cc = u >> 3, k4 = u & 7;
      *(float4*)&wT[cc][k4 * 4] = *(const float4*)(fcW + (size_t)cc * 512 + kc * 32 + k4 * 4);
    }
    __syncthreads();
#pragma unroll
    for (int k4 = 0; k4 < 8; ++k4) {
      float4 w0 = *(float4*)&wT[c4 + 0][k4 * 4];
      float4 w1 = *(float4*)&wT[c4 + 1][k4 * 4];
      float4 w2 = *(float4*)&wT[c4 + 2][k4 * 4];
      float4 w3 = *(float4*)&wT[c4 + 3][k4 * 4];
#pragma unroll
      for (int rr = 0; rr < 8; ++rr) {
        float4 h = *(float4*)&hT[rowg * 8 + rr][k4 * 4];
        acc[rr][0] += h.x * w0.x + h.y * w0.y + h.z * w0.z + h.w * w0.w;
        acc[rr][1] += h.x * w1.x + h.y * w1.y + h.z * w1.z + h.w * w1.w;
        acc[rr][2] += h.x * w2.x + h.y * w2.y + h.z * w2.z + h.w * w2.w;
        acc[rr][3] += h.x * w3.x + h.y * w3.y + h.z * w3.z + h.w * w3.w;
      }
    }
    __syncthreads();
  }
#pragma unroll
  for (int rr = 0; rr < 8; ++rr)
#pragma unroll
    for (int j = 0; j < 4; ++j)
      oL[rowg * 8 + rr][c4 + j] = acc[rr][j] + fcb[c4 + j];
  __syncthreads();
  float a2[8][4];
#pragma unroll
  for (int r = 0; r < 8; ++r)
#pragma unroll
    for (int j = 0; j < 4; ++j) a2[r][j] = 0.f;
#pragma unroll
  for (int k4 = 0; k4 < 32; ++k4) {
    float4 w0 = *(const float4*)(fc2W + (size_t)(c4 + 0) * 128 + k4 * 4);
    float4 w1 = *(const float4*)(fc2W + (size_t)(c4 + 1) * 128 + k4 * 4);
    float4 w2 = *(const float4*)(fc2W + (size_t)(c4 + 2) * 128 + k4 * 4);
    float4 w3 = *(const float4*)(fc2W + (size_t)(c4 + 3) * 128 + k4 * 4);
#pragma unroll
    for (int rr = 0; rr < 8; ++rr) {
      float4 h = *(float4*)&oL[rowg * 8 + rr][k4 * 4];
      a2[rr][0] += h.x * w0.x + h.y * w0.y + h.z * w0.z + h.w * w0.w;
      a2[rr][1] += h.x * w1.x + h.y * w1.y + h.z * w1.z + h.w * w1.w;
      a2[rr][2] += h.x * w2.x + h.y * w2.y + h.z * w2.z + h.w * w2.w;
      a2[rr][3] += h.x * w3.x + h.y * w3.y + h.z * w3.z + h.w * w3.w;
    }
  }
#pragma unroll
  for (int rr = 0; rr < 8; ++rr) {
    const int r = bt0 + rowg * 8 + rr;
#pragma unroll
    for (int j = 0; j < 4; ++j)
      out[(size_t)r * 128 + c4 + j] = a2[rr][j] + fc2b[c4 + j];
  }
}

extern "C" void kernel_launch(void* const* d_in, const int* in_sizes, int n_in,
                              void* d_out, int out_size, void* d_ws, size_t ws_size,
                              hipStream_t stream) {
  (void)in_sizes; (void)n_in; (void)out_size; (void)ws_size;
  const float* x    = (const float*)d_in[0];
  const float* Wih0 = (const float*)d_in[1];
  const float* Whh0 = (const float*)d_in[2];
  const float* bih0 = (const float*)d_in[3];
  const float* bhh0 = (const float*)d_in[4];
  const float* Wih1 = (const float*)d_in[5];
  const float* Whh1 = (const float*)d_in[6];
  const float* bih1 = (const float*)d_in[7];
  const float* bhh1 = (const float*)d_in[8];
  const float* fcW  = (const float*)d_in[9];
  const float* fcb  = (const float*)d_in[10];
  const float* fc2W = (const float*)d_in[11];
  const float* fc2b = (const float*)d_in[12];

  char* ws = (char*)d_ws;
  f16* xT = (f16*)(ws + OFF_XT);
  float* out = (float*)d_out;

  // per-call init: zero slot-0 of both exchange arrays (h[-1] = 0; slot 0 is never verified)
  (void)hipMemsetAsync(ws + OFF_H1S, 0, 32768, stream);
  (void)hipMemsetAsync(ws + OFF_H2S, 0, 32768, stream);

  prep_xT<<<4096, 256, 0, stream>>>(x, xT);
  lstm_persist<<<NWG, THR, 0, stream>>>(Wih0, Whh0, bih0, bhh0,
                                        Wih1, Whh1, bih1, bhh1, ws);
  fc_fused<<<512, 256, 0, stream>>>(ws + OFF_H2S, fcW, fcb, fc2W, fc2b, out);
}

// Round 9
// 5628.241 us; speedup vs baseline: 1.9460x; 1.9460x over previous
//
#include <hip/hip_runtime.h>
#include <math.h>

typedef _Float16 f16;
typedef _Float16 f16x8 __attribute__((ext_vector_type(8)));
typedef _Float16 f16x4 __attribute__((ext_vector_type(4)));
typedef _Float16 f16x2 __attribute__((ext_vector_type(2)));
typedef float f32x4 __attribute__((ext_vector_type(4)));
typedef int i32x4 __attribute__((ext_vector_type(4)));

#define B_ 32
#define T_ 1024
#define I_ 128
#define H_ 512

#define NWG 256        // 1 WG/CU (LDS-bound) -> all resident -> every XCD holds exactly 32
#define THR 512

// ---- workspace layout (bytes) ----
#define C_CNT8  0UL        // 8 x 64B per-XCD rank counters
#define C_DEC   512UL      // decision word
#define C_PROBE 1024UL     // 32 x 64B probe canaries
#define C_MCTR  3072UL     // 32 x 64B probe rendezvous (sc1)
#define C_FLAGF 5120UL     // 32 x 64B fast flags (local-L2 atomic domain)
#define C_FLAGS 7168UL     // 32 x 64B fallback flags (sc1 domain)
// control block ends 9216; memset 16384
#define OFF_H1S 16384UL             // [1025][32768] slot k = h1[t=k-1]; [wg][32b x 16c f16]
#define OFF_H2S 33603584UL          // [1025][32768] slot k = h2[t=k-1]
#define OFF_XT  67190784UL          // f16 [1024][32][128] = 8,388,608
// total 75,579,392 B

__device__ inline f32x4 mfma16(f16x8 a, f16x8 b, f32x4 c) {
  return __builtin_amdgcn_mfma_f32_16x16x32_f16(a, b, c, 0, 0, 0);
}
__device__ inline float fast_sig(float x) { return 1.f / (1.f + __expf(-x)); }
__device__ inline float fast_tanh(float x) {
  float e = __expf(-2.f * fabsf(x));
  float t = (1.f - e) / (1.f + e);
  return x < 0.f ? -t : t;
}

// ---- protocol primitives ----
// sc1 (MALL/device scope) — R2/R6-proven
__device__ inline unsigned ld_sc1_u32(const unsigned* p) {
  unsigned r;
  asm volatile("global_load_dword %0, %1, off sc1\n\ts_waitcnt vmcnt(0)"
               : "=v"(r) : "v"(p) : "memory");
  return r;
}
__device__ inline void st_sc1_u32(unsigned* p, unsigned v) {
  asm volatile("global_store_dword %0, %1, off sc1" :: "v"(p), "v"(v) : "memory");
}
// local-L2 atomics — executed at the XCD L2 (always fresh); R5-verified livelock-free
__device__ inline unsigned atomic_add0_local(unsigned* p) {
  unsigned old, zero = 0;
  asm volatile("global_atomic_add %0, %1, %2, off sc0\n\ts_waitcnt vmcnt(0)"
               : "=v"(old) : "v"(p), "v"(zero) : "memory");
  return old;
}
__device__ inline void atomic_swap_local(unsigned* p, unsigned v) {
  asm volatile("global_atomic_swap %0, %1, off" :: "v"(p), "v"(v) : "memory");
}
__device__ inline void wait_vm0() {
  asm volatile("s_waitcnt vmcnt(0)" ::: "memory");
  __builtin_amdgcn_sched_barrier(0);
}

// LDS XOR-swizzle (R2/R6-proven)
__device__ inline int swz_h(int b, int kbyte) { return b * 1024 + (kbyte ^ ((b & 7) << 4)); }
__device__ inline int swz_x(int b, int kbyte) { return b * 256  + (kbyte ^ ((b & 7) << 4)); }

// x[b][t][i] f32 -> xT[t][b][i] f16
__global__ __launch_bounds__(256) void prep_xT(const float* __restrict__ x, f16* __restrict__ xT) {
  const int idx = blockIdx.x * 256 + threadIdx.x;
  const int n4 = B_ * T_ * I_ / 4;
  if (idx < n4) {
    const int i4 = idx * 4;
    const int i  = i4 & (I_ - 1);
    const int tt = (i4 >> 7) & (T_ - 1);
    const int b  = i4 >> 17;
    float4 v = *(const float4*)(x + i4);
    f16x4 o;
    o[0] = (f16)v.x; o[1] = (f16)v.y; o[2] = (f16)v.z; o[3] = (f16)v.w;
    *(f16x4*)(xT + ((size_t)tt * B_ + b) * I_ + i) = o;
  }
}

// Persistent merged 2-layer LSTM (R6 algorithm); 32 co-XCD WGs; L2-local sync when verified.
__global__ __launch_bounds__(THR, 1) void lstm_persist(
    const float* __restrict__ Wih0, const float* __restrict__ Whh0,
    const float* __restrict__ bih0, const float* __restrict__ bhh0,
    const float* __restrict__ Wih1, const float* __restrict__ Whh1,
    const float* __restrict__ bih1, const float* __restrict__ bhh1,
    char* ws) {
  __shared__ i32x4 h1l4[2048];         // 32KB  h1[s-1] (swizzled)
  __shared__ i32x4 h2l4[2048];         // 32KB  h2[s-2] (swizzled)
  __shared__ i32x4 xl4[512];           // 8KB   x[s] (swizzled)
  __shared__ float g0[2 * 32 * 68];    // L0 gate partials
  __shared__ float g1[2 * 32 * 68];    // L1 gate partials
  __shared__ float bias0[64], bias1[64];
  __shared__ int shi[8];

  const int tid  = threadIdx.x;
  const int lane = tid & 63;
  const int wv   = tid >> 6;
  const int nt   = wv & 3;
  const int kh   = wv >> 2;
  const int cfr  = lane & 15;
  const int ksub = lane >> 4;

  unsigned* cnt8   = (unsigned*)(ws + C_CNT8);
  unsigned* dec    = (unsigned*)(ws + C_DEC);
  unsigned* probe  = (unsigned*)(ws + C_PROBE);
  unsigned* mctr   = (unsigned*)(ws + C_MCTR);
  unsigned* flagsF = (unsigned*)(ws + C_FLAGF);
  unsigned* flagsS = (unsigned*)(ws + C_FLAGS);
  const char* h1base = ws + OFF_H1S;
  const char* h2base = ws + OFF_H2S;

  // ---- census: rank within own XCD (device-scope atomics) ----
  if (tid == 0) {
    shi[3] = 1; shi[4] = 1;
    unsigned xcc = __builtin_amdgcn_s_getreg(6164) & 7u;   // HW_REG_XCC_ID
    unsigned rk = atomicAdd(cnt8 + xcc * 16, 1u);
    shi[0] = (int)xcc; shi[1] = (int)rk;
  }
  __syncthreads();
  const int myxcd = shi[0], myrank = shi[1];

  // ---- leader picks the first XCD that filled to 32 (pigeonhole: guaranteed) ----
  if (blockIdx.x == 0 && tid == 0) {
    unsigned enc = 0x80000000u;
    for (int it = 0; it < (1 << 22); ++it) {
      int a = -1;
      for (int x2 = 0; x2 < 8; ++x2)
        if (atomicAdd(cnt8 + x2 * 16, 0u) >= 32u) { a = x2; break; }
      if (a >= 0) { enc |= 0x100u | (unsigned)a; break; }
      __builtin_amdgcn_s_sleep(8);
    }
    atomicExch(dec, enc);
  }
  if (tid == 0) {
    unsigned d = 0;
    for (int it = 0; it < (1 << 22); ++it) {
      d = atomicAdd(dec, 0u);
      if (d & 0x80000000u) break;
      __builtin_amdgcn_s_sleep(4);
    }
    if (!(d & 0x80000000u)) d = 0x80000000u;
    ((unsigned*)shi)[2] = d;
  }
  __syncthreads();
  const unsigned dv = ((unsigned*)shi)[2];
  const bool cand = (dv & 0x100u) != 0;
  int gid = -1;
  if (cand) { if (myxcd == (int)(dv & 7u) && myrank < 32) gid = myrank; }
  else      { if (blockIdx.x < 32) gid = blockIdx.x; }
  __syncthreads();
  if (gid < 0) return;

  // ---- probe: plain-store -> {L2-atomic read, plain cold read} within the group ----
  if (tid == 0) {
    *(volatile unsigned*)(probe + gid * 16)     = 0xC0DE0000u + (unsigned)gid;
    *(volatile unsigned*)(probe + gid * 16 + 8) = 0xFACE0000u + (unsigned)gid;
  }
  wait_vm0();
  __syncthreads();
  if (tid == 0) st_sc1_u32(mctr + gid * 16, 1u);
  if (tid < 64) {
    const bool act = tid < 32;
    for (int it = 0; it < (1 << 22); ++it) {
      unsigned v = act ? ld_sc1_u32(mctr + tid * 16) : 1u;
      if (__all((int)(v >= 1u))) break;
      __builtin_amdgcn_s_sleep(2);
    }
  }
  __syncthreads();
  if (tid < 32) {
    unsigned va = atomic_add0_local(probe + tid * 16);
    unsigned vb = *(volatile unsigned*)(probe + tid * 16 + 8);
    if (!((va == 0xC0DE0000u + (unsigned)tid) && (vb == 0xFACE0000u + (unsigned)tid)))
      shi[3] = 0;
  }
  __syncthreads();
  const int grpok = shi[3];
  if (tid == 0) st_sc1_u32(mctr + gid * 16, grpok ? 3u : 2u);
  if (tid < 64) {
    const bool act = tid < 32;
    for (int it = 0; it < (1 << 22); ++it) {
      unsigned v = act ? ld_sc1_u32(mctr + tid * 16) : 2u;
      if (__all((int)(v >= 2u))) break;
      __builtin_amdgcn_s_sleep(2);
    }
  }
  __syncthreads();
  if (tid < 32) { if (ld_sc1_u32(mctr + tid * 16) != 3u) shi[4] = 0; }
  __syncthreads();
  const bool fast = cand && (shi[4] != 0);
  __syncthreads();

  if (tid < 64) {
    const int g = tid >> 4, hc = tid & 15;
    const int row = g * 512 + gid * 16 + hc;
    bias0[tid] = bih0[row] + bhh0[row];
    bias1[tid] = bih1[row] + bhh1[row];
  }

  // ---- weight preload into VGPRs (R6-identical, wg -> gid) ----
  const int gc  = nt * 16 + cfr;
  const int row = (gc >> 4) * 512 + gid * 16 + (gc & 15);
  f16x8 wa[10];
#pragma unroll
  for (int ksl = 0; ksl < 10; ++ksl) {
    const int k = (kh * 10 + ksl) * 32 + ksub * 8;
    const float* src = (k < I_) ? (Wih0 + (size_t)row * I_ + k)
                                : (Whh0 + (size_t)row * H_ + (k - I_));
    float4 v0 = *(const float4*)(src);
    float4 v1 = *(const float4*)(src + 4);
    f16x8 h;
    h[0] = (f16)v0.x; h[1] = (f16)v0.y; h[2] = (f16)v0.z; h[3] = (f16)v0.w;
    h[4] = (f16)v1.x; h[5] = (f16)v1.y; h[6] = (f16)v1.z; h[7] = (f16)v1.w;
    wa[ksl] = h;
  }
  f16x8 wb[16];
#pragma unroll
  for (int ksl = 0; ksl < 16; ++ksl) {
    const int k = (kh * 16 + ksl) * 32 + ksub * 8;
    const float* src = (k < H_) ? (Wih1 + (size_t)row * H_ + k)
                                : (Whh1 + (size_t)row * H_ + (k - H_));
    float4 v0 = *(const float4*)(src);
    float4 v1 = *(const float4*)(src + 4);
    f16x8 h;
    h[0] = (f16)v0.x; h[1] = (f16)v0.y; h[2] = (f16)v0.z; h[3] = (f16)v0.w;
    h[4] = (f16)v1.x; h[5] = (f16)v1.y; h[6] = (f16)v1.z; h[7] = (f16)v1.w;
    wb[ksl] = h;
  }

  float cst0 = 0.f, cst1 = 0.f;        // L0 cell state (threads 0..255)
  float dst0 = 0.f, dst1 = 0.f;        // L1 cell state (threads 256..511)
  const char* h1c = (const char*)h1l4;
  const char* h2c = (const char*)h2l4;
  const char* xc  = (const char*)xl4;

  __syncthreads();

  for (int s = 0; s <= T_; ++s) {
    i32x4 xv;
    const bool hasx = (s < T_);
    if (hasx) xv = ((const i32x4*)(ws + OFF_XT))[(size_t)s * 512 + tid];

    // ---- gate: all 32 flags >= s (h1[s-1] slot s, h2[s-2] slot s-1 published) ----
    if (s >= 1) {
      if (tid < 64) {
        const unsigned tgt = (unsigned)s;
        const bool act = tid < 32;
        if (fast) {
          for (int it = 0; it < (1 << 20); ++it) {
            unsigned v = act ? atomic_add0_local(flagsF + tid * 16) : tgt;
            if (__all((int)(v >= tgt))) break;
            __builtin_amdgcn_s_sleep(1);
          }
        } else {
          for (;;) {
            unsigned v = act ? ld_sc1_u32(flagsS + tid * 16) : tgt;
            if (__all((int)(v >= tgt))) break;
            __builtin_amdgcn_s_sleep(1);
          }
        }
      }
      __syncthreads();
    }

    // ---- stage: plain cold loads (fast: local-L2 hit; fallback: MALL) -> swizzled LDS ----
    {
      const i32x4* src = (const i32x4*)(h1base + (size_t)s * 32768);
#pragma unroll
      for (int r = 0; r < 4; ++r) {
        const int u = r * 512 + tid;
        i32x4 v = src[u];
        const int wgs = u >> 6, b = (u >> 1) & 31, half = u & 1;
        *(i32x4*)((char*)h1l4 + swz_h(b, wgs * 32 + half * 16)) = v;
      }
    }
    if (s >= 1) {
      const i32x4* src = (const i32x4*)(h2base + (size_t)(s - 1) * 32768);
#pragma unroll
      for (int r = 0; r < 4; ++r) {
        const int u = r * 512 + tid;
        i32x4 v = src[u];
        const int wgs = u >> 6, b = (u >> 1) & 31, half = u & 1;
        *(i32x4*)((char*)h2l4 + swz_h(b, wgs * 32 + half * 16)) = v;
      }
    }
    if (hasx) *(i32x4*)((char*)xl4 + swz_x(tid >> 4, (tid & 15) * 16)) = xv;
    __syncthreads();

    // ---- MFMA phase (R6-identical) ----
    if (s < T_) {
      f32x4 a0 = {0.f, 0.f, 0.f, 0.f}, a1 = {0.f, 0.f, 0.f, 0.f};
#pragma unroll
      for (int ksl = 0; ksl < 10; ++ksl) {
        const int k = (kh * 10 + ksl) * 32 + ksub * 8;
        f16x8 af0, af1;
        if (k < I_) {
          af0 = *(const f16x8*)(xc + swz_x(cfr,      k * 2));
          af1 = *(const f16x8*)(xc + swz_x(16 + cfr, k * 2));
        } else {
          af0 = *(const f16x8*)(h1c + swz_h(cfr,      (k - I_) * 2));
          af1 = *(const f16x8*)(h1c + swz_h(16 + cfr, (k - I_) * 2));
        }
        a0 = mfma16(af0, wa[ksl], a0);
        a1 = mfma16(af1, wa[ksl], a1);
      }
      const int base = kh * 2176 + (ksub * 4) * 68 + nt * 16 + cfr;
#pragma unroll
      for (int r = 0; r < 4; ++r) {
        g0[base + r * 68]           = a0[r];
        g0[base + 16 * 68 + r * 68] = a1[r];
      }
    }
    if (s >= 1) {
      f32x4 a0 = {0.f, 0.f, 0.f, 0.f}, a1 = {0.f, 0.f, 0.f, 0.f};
#pragma unroll
      for (int ksl = 0; ksl < 16; ++ksl) {
        const int k = (kh * 16 + ksl) * 32 + ksub * 8;
        f16x8 af0, af1;
        if (k < H_) {
          af0 = *(const f16x8*)(h1c + swz_h(cfr,      k * 2));
          af1 = *(const f16x8*)(h1c + swz_h(16 + cfr, k * 2));
        } else {
          af0 = *(const f16x8*)(h2c + swz_h(cfr,      (k - H_) * 2));
          af1 = *(const f16x8*)(h2c + swz_h(16 + cfr, (k - H_) * 2));
        }
        a0 = mfma16(af0, wb[ksl], a0);
        a1 = mfma16(af1, wb[ksl], a1);
      }
      const int base = kh * 2176 + (ksub * 4) * 68 + nt * 16 + cfr;
#pragma unroll
      for (int r = 0; r < 4; ++r) {
        g1[base + r * 68]           = a0[r];
        g1[base + 16 * 68 + r * 68] = a1[r];
      }
    }
    __syncthreads();

    // ---- pointwise + block-contiguous data store (fast: plain; fallback: sc1) ----
    if (s < T_ && tid < 256) {         // L0 -> H1S slot s+1
      const int rb = tid >> 3, hp = tid & 7;
      const float* gr = g0 + rb * 68;
      float hv[2];
#pragma unroll
      for (int cc = 0; cc < 2; ++cc) {
        const int c = 2 * hp + cc;
        const float pi = gr[c]      + gr[2176 + c]      + bias0[c];
        const float pf = gr[16 + c] + gr[2176 + 16 + c] + bias0[16 + c];
        const float pg = gr[32 + c] + gr[2176 + 32 + c] + bias0[32 + c];
        const float po = gr[48 + c] + gr[2176 + 48 + c] + bias0[48 + c];
        const float ig = fast_sig(pi), fg = fast_sig(pf);
        const float gg = fast_tanh(pg), og = fast_sig(po);
        const float cprev = cc ? cst1 : cst0;
        const float cnew = fg * cprev + ig * gg;
        if (cc) cst1 = cnew; else cst0 = cnew;
        hv[cc] = og * fast_tanh(cnew);
      }
      f16x2 pk; pk[0] = (f16)hv[0]; pk[1] = (f16)hv[1];
      const unsigned dw = __builtin_bit_cast(unsigned, pk);
      unsigned* dst = (unsigned*)(h1base + (size_t)(s + 1) * 32768 +
                                  (size_t)gid * 1024 + rb * 32 + hp * 4);
      if (fast) *(volatile unsigned*)dst = dw; else st_sc1_u32(dst, dw);
    }
    if (s >= 1 && tid >= 256) {        // L1 -> H2S slot s
      const int t2 = tid - 256;
      const int rb = t2 >> 3, hp = t2 & 7;
      const float* gr = g1 + rb * 68;
      float hv[2];
#pragma unroll
      for (int cc = 0; cc < 2; ++cc) {
        const int c = 2 * hp + cc;
        const float pi = gr[c]      + gr[2176 + c]      + bias1[c];
        const float pf = gr[16 + c] + gr[2176 + 16 + c] + bias1[16 + c];
        const float pg = gr[32 + c] + gr[2176 + 32 + c] + bias1[32 + c];
        const float po = gr[48 + c] + gr[2176 + 48 + c] + bias1[48 + c];
        const float ig = fast_sig(pi), fg = fast_sig(pf);
        const float gg = fast_tanh(pg), og = fast_sig(po);
        const float cprev = cc ? dst1 : dst0;
        const float cnew = fg * cprev + ig * gg;
        if (cc) dst1 = cnew; else dst0 = cnew;
        hv[cc] = og * fast_tanh(cnew);
      }
      f16x2 pk; pk[0] = (f16)hv[0]; pk[1] = (f16)hv[1];
      const unsigned dw = __builtin_bit_cast(unsigned, pk);
      unsigned* dst = (unsigned*)(h2base + (size_t)s * 32768 +
                                  (size_t)gid * 1024 + rb * 32 + hp * 4);
      if (fast) *(volatile unsigned*)dst = dw; else st_sc1_u32(dst, dw);
    }

    // ---- publish: drain all waves' stores, then one flag ----
    asm volatile("s_waitcnt vmcnt(0)" ::: "memory");
    __syncthreads();
    if (tid == 0) {
      if (fast) atomic_swap_local(flagsF + gid * 16, (unsigned)(s + 1));
      else      st_sc1_u32(flagsS + gid * 16, (unsigned)(s + 1));
    }
    __builtin_amdgcn_sched_barrier(0);
  }
}

// fused FC1+FC2 reading block layout (R6-identical): rows bt = b*1024 + t.
__global__ __launch_bounds__(256) void fc_fused(const char* __restrict__ ws_h2,
                                                const float* __restrict__ fcW,
                                                const float* __restrict__ fcb,
                                                const float* __restrict__ fc2W,
                                                const float* __restrict__ fc2b,
                                                float* __restrict__ out) {
  __shared__ float hT[64][36];
  __shared__ float wT[128][36];
  __shared__ float oL[64][136];
  const int bt0 = blockIdx.x * 64;
  const int b   = bt0 >> 10;
  const int t0  = bt0 & 1023;
  const int t = threadIdx.x;
  const int c4 = (t & 31) * 4;
  const int rowg = t >> 5;
  float acc[8][4];
#pragma unroll
  for (int r = 0; r < 8; ++r)
#pragma unroll
    for (int j = 0; j < 4; ++j) acc[r][j] = 0.f;

  for (int kc = 0; kc < 16; ++kc) {
    {
      const int r = t >> 2, q = t & 3;
      const int c0 = kc * 32 + q * 8;
      const f16x8 v = *(const f16x8*)(ws_h2 + (size_t)(t0 + r + 1) * 32768 +
                                      (size_t)(c0 >> 4) * 1024 + b * 32 + (c0 & 15) * 2);
#pragma unroll
      for (int j = 0; j < 8; ++j) hT[r][q * 8 + j] = (float)v[j];
    }
#pragma unroll
    for (int u = t; u < 1024; u += 256) {
      const int cc = u >> 3, k4 = u & 7;
      *(float4*)&wT[cc][k4 * 4] = *(const float4*)(fcW + (size_t)cc * 512 + kc * 32 + k4 * 4);
    }
    __syncthreads();
#pragma unroll
    for (int k4 = 0; k4 < 8; ++k4) {
      float4 w0 = *(float4*)&wT[c4 + 0][k4 * 4];
      float4 w1 = *(float4*)&wT[c4 + 1][k4 * 4];
      float4 w2 = *(float4*)&wT[c4 + 2][k4 * 4];
      float4 w3 = *(float4*)&wT[c4 + 3][k4 * 4];
#pragma unroll
      for (int rr = 0; rr < 8; ++rr) {
        float4 h = *(float4*)&hT[rowg * 8 + rr][k4 * 4];
        acc[rr][0] += h.x * w0.x + h.y * w0.y + h.z * w0.z + h.w * w0.w;
        acc[rr][1] += h.x * w1.x + h.y * w1.y + h.z * w1.z + h.w * w1.w;
        acc[rr][2] += h.x * w2.x + h.y * w2.y + h.z * w2.z + h.w * w2.w;
        acc[rr][3] += h.x * w3.x + h.y * w3.y + h.z * w3.z + h.w * w3.w;
      }
    }
    __syncthreads();
  }
#pragma unroll
  for (int rr = 0; rr < 8; ++rr)
#pragma unroll
    for (int j = 0; j < 4; ++j)
      oL[rowg * 8 + rr][c4 + j] = acc[rr][j] + fcb[c4 + j];
  __syncthreads();
  float a2[8][4];
#pragma unroll
  for (int r = 0; r < 8; ++r)
#pragma unroll
    for (int j = 0; j < 4; ++j) a2[r][j] = 0.f;
#pragma unroll
  for (int k4 = 0; k4 < 32; ++k4) {
    float4 w0 = *(const float4*)(fc2W + (size_t)(c4 + 0) * 128 + k4 * 4);
    float4 w1 = *(const float4*)(fc2W + (size_t)(c4 + 1) * 128 + k4 * 4);
    float4 w2 = *(const float4*)(fc2W + (size_t)(c4 + 2) * 128 + k4 * 4);
    float4 w3 = *(const float4*)(fc2W + (size_t)(c4 + 3) * 128 + k4 * 4);
#pragma unroll
    for (int rr = 0; rr < 8; ++rr) {
      float4 h = *(float4*)&oL[rowg * 8 + rr][k4 * 4];
      a2[rr][0] += h.x * w0.x + h.y * w0.y + h.z * w0.z + h.w * w0.w;
      a2[rr][1] += h.x * w1.x + h.y * w1.y + h.z * w1.z + h.w * w1.w;
      a2[rr][2] += h.x * w2.x + h.y * w2.y + h.z * w2.z + h.w * w2.w;
      a2[rr][3] += h.x * w3.x + h.y * w3.y + h.z * w3.z + h.w * w3.w;
    }
  }
#pragma unroll
  for (int rr = 0; rr < 8; ++rr) {
    const int r = bt0 + rowg * 8 + rr;
#pragma unroll
    for (int j = 0; j < 4; ++j)
      out[(size_t)r * 128 + c4 + j] = a2[rr][j] + fc2b[c4 + j];
  }
}

extern "C" void kernel_launch(void* const* d_in, const int* in_sizes, int n_in,
                              void* d_out, int out_size, void* d_ws, size_t ws_size,
                              hipStream_t stream) {
  (void)in_sizes; (void)n_in; (void)out_size; (void)ws_size;
  const float* x    = (const float*)d_in[0];
  const float* Wih0 = (const float*)d_in[1];
  const float* Whh0 = (const float*)d_in[2];
  const float* bih0 = (const float*)d_in[3];
  const float* bhh0 = (const float*)d_in[4];
  const float* Wih1 = (const float*)d_in[5];
  const float* Whh1 = (const float*)d_in[6];
  const float* bih1 = (const float*)d_in[7];
  const float* bhh1 = (const float*)d_in[8];
  const float* fcW  = (const float*)d_in[9];
  const float* fcb  = (const float*)d_in[10];
  const float* fc2W = (const float*)d_in[11];
  const float* fc2b = (const float*)d_in[12];

  char* ws = (char*)d_ws;
  f16* xT = (f16*)(ws + OFF_XT);
  float* out = (float*)d_out;

  // per-call init: control block + zero slot-0 of both exchange arrays (h[-1] = 0)
  (void)hipMemsetAsync(ws, 0, 16384, stream);
  (void)hipMemsetAsync(ws + OFF_H1S, 0, 32768, stream);
  (void)hipMemsetAsync(ws + OFF_H2S, 0, 32768, stream);

  prep_xT<<<4096, 256, 0, stream>>>(x, xT);
  lstm_persist<<<NWG, THR, 0, stream>>>(Wih0, Whh0, bih0, bhh0,
                                        Wih1, Whh1, bih1, bhh1, ws);
  fc_fused<<<512, 256, 0, stream>>>(ws + OFF_H2S, fcW, fcb, fc2W, fc2b, out);
}

// Round 10
// 4340.917 us; speedup vs baseline: 2.5230x; 1.2966x over previous
//
#include <hip/hip_runtime.h>
#include <math.h>

typedef _Float16 f16;
typedef _Float16 f16x8 __attribute__((ext_vector_type(8)));
typedef _Float16 f16x4 __attribute__((ext_vector_type(4)));
typedef _Float16 f16x2 __attribute__((ext_vector_type(2)));
typedef float f32x16 __attribute__((ext_vector_type(16)));
typedef int i32x4 __attribute__((ext_vector_type(4)));

#define B_ 32
#define T_ 1024
#define I_ 128
#define H_ 512

#define NWG 32
#define THR 512

// ---- workspace layout (bytes) — R6-identical ----
#define OFF_FLAGS 0UL                 // 32 x 64B flags = 2048
#define OFF_H1S   4096UL              // [1025][32768] slot k = h1[t=k-1]; [wg][32b x 16c f16]
#define OFF_H2S   33591296UL          // [1025][32768] slot k = h2[t=k-1]
#define OFF_XT    67178496UL          // f16 [1024][32][128] = 8,388,608
// total 75,567,104 B

__device__ inline f32x16 mfma32(f16x8 a, f16x8 b, f32x16 c) {
  return __builtin_amdgcn_mfma_f32_32x32x16_f16(a, b, c, 0, 0, 0);
}
__device__ inline float fast_sig(float x) { return 1.f / (1.f + __expf(-x)); }
__device__ inline float fast_tanh(float x) {
  float e = __expf(-2.f * fabsf(x));
  float t = (1.f - e) / (1.f + e);
  return x < 0.f ? -t : t;
}

// sc1 = device-coherent (MALL) protocol primitives — R2/R6-proven
__device__ inline unsigned ld_sc1_u32(const unsigned* p) {
  unsigned r;
  asm volatile("global_load_dword %0, %1, off sc1\n\ts_waitcnt vmcnt(0)"
               : "=v"(r) : "v"(p) : "memory");
  return r;
}
__device__ inline void st_sc1_u32(unsigned* p, unsigned v) {
  asm volatile("global_store_dword %0, %1, off sc1" :: "v"(p), "v"(v) : "memory");
}

// LDS XOR-swizzle (R2/R6-proven; even bank spread for 32-row b128 reads)
__device__ inline int swz_h(int b, int kbyte) { return b * 1024 + (kbyte ^ ((b & 7) << 4)); }
__device__ inline int swz_x(int b, int kbyte) { return b * 256  + (kbyte ^ ((b & 7) << 4)); }

// x[b][t][i] f32 -> xT[t][b][i] f16
__global__ __launch_bounds__(256) void prep_xT(const float* __restrict__ x, f16* __restrict__ xT) {
  const int idx = blockIdx.x * 256 + threadIdx.x;
  const int n4 = B_ * T_ * I_ / 4;
  if (idx < n4) {
    const int i4 = idx * 4;
    const int i  = i4 & (I_ - 1);
    const int tt = (i4 >> 7) & (T_ - 1);
    const int b  = i4 >> 17;
    float4 v = *(const float4*)(x + i4);
    f16x4 o;
    o[0] = (f16)v.x; o[1] = (f16)v.y; o[2] = (f16)v.z; o[3] = (f16)v.w;
    *(f16x4*)(xT + ((size_t)tt * B_ + b) * I_ + i) = o;
  }
}

// Persistent merged 2-layer LSTM (R6 protocol/schedule), 32x32x16 MFMA tiling.
// Waves 0-3: L0 (nt = wv&1 col-tile of 32, kq = (wv>>1)&1 K-half of 640).
// Waves 4-7: L1 (nt, kq over K=1024; kq=0 -> h1 half, kq=1 -> h2 half).
__global__ __launch_bounds__(THR, 1) void lstm_persist(
    const float* __restrict__ Wih0, const float* __restrict__ Whh0,
    const float* __restrict__ bih0, const float* __restrict__ bhh0,
    const float* __restrict__ Wih1, const float* __restrict__ Whh1,
    const float* __restrict__ bih1, const float* __restrict__ bhh1,
    char* ws) {
  __shared__ i32x4 h1l4[2048];          // 32KB  h1[s-1] (swizzled)
  __shared__ i32x4 h2l4[2048];          // 32KB  h2[s-2] (swizzled)
  __shared__ i32x4 xl4[512];            // 8KB   x[s] (swizzled)
  __shared__ float g0[2 * 32 * 68];     // L0 gate partials [kq][32b][64c pad 68]
  __shared__ float g1[2 * 32 * 68];     // L1 gate partials
  __shared__ float bias0[64], bias1[64];

  const int tid  = threadIdx.x;
  const int wg   = blockIdx.x;
  const int lane = tid & 63;
  const int wv   = tid >> 6;
  const int role = wv >> 2;             // 0 = L0, 1 = L1
  const int nt   = wv & 1;              // 32-col N-tile
  const int kq   = (wv >> 1) & 1;       // K-half
  const int bl   = lane & 31;           // A row / B col within tile
  const int kg   = lane >> 5;           // k-subgroup (x8)

  unsigned* flags = (unsigned*)(ws + OFF_FLAGS);
  const char* h1base = ws + OFF_H1S;
  const char* h2base = ws + OFF_H2S;

  if (tid < 64) {
    const int g = tid >> 4, hc = tid & 15;
    const int row = g * 512 + wg * 16 + hc;
    bias0[tid] = bih0[row] + bhh0[row];
    bias1[tid] = bih1[row] + bhh1[row];
  }

  // ---- weight preload into VGPRs (B-frag: lane bl = col n, kg = k-subgroup) ----
  const int n    = nt * 32 + bl;        // gate-col 0..63
  const int wrow = (n >> 4) * 512 + wg * 16 + (n & 15);
  f16x8 wreg[32];
  if (role == 0) {
#pragma unroll
    for (int ks = 0; ks < 20; ++ks) {
      const int k = kq * 320 + ks * 16 + kg * 8;
      const float* src = (k < I_) ? (Wih0 + (size_t)wrow * I_ + k)
                                  : (Whh0 + (size_t)wrow * H_ + (k - I_));
      float4 v0 = *(const float4*)(src);
      float4 v1 = *(const float4*)(src + 4);
      f16x8 h;
      h[0] = (f16)v0.x; h[1] = (f16)v0.y; h[2] = (f16)v0.z; h[3] = (f16)v0.w;
      h[4] = (f16)v1.x; h[5] = (f16)v1.y; h[6] = (f16)v1.z; h[7] = (f16)v1.w;
      wreg[ks] = h;
    }
  } else {
#pragma unroll
    for (int ks = 0; ks < 32; ++ks) {
      const int k = kq * 512 + ks * 16 + kg * 8;
      const float* src = (k < H_) ? (Wih1 + (size_t)wrow * H_ + k)
                                  : (Whh1 + (size_t)wrow * H_ + (k - H_));
      float4 v0 = *(const float4*)(src);
      float4 v1 = *(const float4*)(src + 4);
      f16x8 h;
      h[0] = (f16)v0.x; h[1] = (f16)v0.y; h[2] = (f16)v0.z; h[3] = (f16)v0.w;
      h[4] = (f16)v1.x; h[5] = (f16)v1.y; h[6] = (f16)v1.z; h[7] = (f16)v1.w;
      wreg[ks] = h;
    }
  }

  float cst0 = 0.f, cst1 = 0.f;         // L0 cell state (threads 0..255)
  float dst0 = 0.f, dst1 = 0.f;         // L1 cell state (threads 256..511)
  const char* h1c = (const char*)h1l4;
  const char* h2c = (const char*)h2l4;
  const char* xc  = (const char*)xl4;

  __syncthreads();

  for (int s = 0; s <= T_; ++s) {
    // prefetch x[s] (plain; independent of flag)
    i32x4 xv;
    const bool hasx = (s < T_);
    if (hasx) xv = ((const i32x4*)(ws + OFF_XT))[(size_t)s * 512 + tid];

    // ---- gate: flag >= s confirms h1[s-1] (slot s) and h2[s-2] (slot s-1) ----
    if (s >= 1) {
      if (tid < 64) {
        const unsigned tgt = (unsigned)s;
        const unsigned* fp = flags + (tid < NWG ? tid : 0) * 16;
        const bool active = tid < NWG;
        for (;;) {
          unsigned v = ld_sc1_u32(fp);
          if (!active) v = tgt;
          if (__all((int)(v >= tgt))) break;
          __builtin_amdgcn_s_sleep(1);
        }
      }
      __syncthreads();
    }

    // ---- stage phase: block-linear plain cold loads -> swizzled LDS (R6) ----
    {
      const i32x4* src = (const i32x4*)(h1base + (size_t)s * 32768);
#pragma unroll
      for (int r = 0; r < 4; ++r) {
        const int u = r * 512 + tid;
        i32x4 v = src[u];
        const int wgs = u >> 6, b = (u >> 1) & 31, half = u & 1;
        *(i32x4*)((char*)h1l4 + swz_h(b, wgs * 32 + half * 16)) = v;
      }
    }
    if (s >= 1) {
      const i32x4* src = (const i32x4*)(h2base + (size_t)(s - 1) * 32768);
#pragma unroll
      for (int r = 0; r < 4; ++r) {
        const int u = r * 512 + tid;
        i32x4 v = src[u];
        const int wgs = u >> 6, b = (u >> 1) & 31, half = u & 1;
        *(i32x4*)((char*)h2l4 + swz_h(b, wgs * 32 + half * 16)) = v;
      }
    }
    if (hasx) *(i32x4*)((char*)xl4 + swz_x(tid >> 4, (tid & 15) * 16)) = xv;
    __syncthreads();

    // ---- MFMA phase: 32x32x16, one A-read per MFMA, A shared across full batch tile ----
    if (role == 0) {
      if (s < T_) {                      // L0: gates[s] = [x_s | h1_{s-1}] @ W0^T
        f32x16 acc = {};
        if (kq == 0) {
#pragma unroll
          for (int ks = 0; ks < 8; ++ks) {          // k = ks*16+kg*8 < 128 -> x
            f16x8 a = *(const f16x8*)(xc + swz_x(bl, (ks * 16 + kg * 8) * 2));
            acc = mfma32(a, wreg[ks], acc);
          }
#pragma unroll
          for (int ks = 8; ks < 20; ++ks) {         // h1[k-128]
            f16x8 a = *(const f16x8*)(h1c + swz_h(bl, (ks * 16 + kg * 8 - I_) * 2));
            acc = mfma32(a, wreg[ks], acc);
          }
        } else {
#pragma unroll
          for (int ks = 0; ks < 20; ++ks) {         // k = 320+ks*16+kg*8 -> h1[k-128]
            f16x8 a = *(const f16x8*)(h1c + swz_h(bl, (192 + ks * 16 + kg * 8) * 2));
            acc = mfma32(a, wreg[ks], acc);
          }
        }
        const int cb = nt * 32 + bl;
#pragma unroll
        for (int r = 0; r < 16; ++r) {
          const int row = (r & 3) + 8 * (r >> 2) + 4 * kg;   // m74-verified C/D layout
          g0[kq * 2176 + row * 68 + cb] = acc[r];
        }
      }
    } else {
      if (s >= 1) {                      // L1: gates[s-1] = [h1_{s-1} | h2_{s-2}] @ W1^T
        f32x16 acc = {};
        if (kq == 0) {
#pragma unroll
          for (int ks = 0; ks < 32; ++ks) {         // k<512 -> h1
            f16x8 a = *(const f16x8*)(h1c + swz_h(bl, (ks * 16 + kg * 8) * 2));
            acc = mfma32(a, wreg[ks], acc);
          }
        } else {
#pragma unroll
          for (int ks = 0; ks < 32; ++ks) {         // k>=512 -> h2
            f16x8 a = *(const f16x8*)(h2c + swz_h(bl, (ks * 16 + kg * 8) * 2));
            acc = mfma32(a, wreg[ks], acc);
          }
        }
        const int cb = nt * 32 + bl;
#pragma unroll
        for (int r = 0; r < 16; ++r) {
          const int row = (r & 3) + 8 * (r >> 2) + 4 * kg;
          g1[kq * 2176 + row * 68 + cb] = acc[r];
        }
      }
    }
    __syncthreads();

    // ---- pointwise + coalesced block-contiguous sc1 store (R6-identical) ----
    if (s < T_ && tid < 256) {           // L0 -> H1S slot s+1
      const int rb = tid >> 3, hp = tid & 7;
      const float* gr = g0 + rb * 68;
      float hv[2];
#pragma unroll
      for (int cc = 0; cc < 2; ++cc) {
        const int c = 2 * hp + cc;
        const float pi = gr[c]      + gr[2176 + c]      + bias0[c];
        const float pf = gr[16 + c] + gr[2176 + 16 + c] + bias0[16 + c];
        const float pg = gr[32 + c] + gr[2176 + 32 + c] + bias0[32 + c];
        const float po = gr[48 + c] + gr[2176 + 48 + c] + bias0[48 + c];
        const float ig = fast_sig(pi), fg = fast_sig(pf);
        const float gg = fast_tanh(pg), og = fast_sig(po);
        const float cprev = cc ? cst1 : cst0;
        const float cnew = fg * cprev + ig * gg;
        if (cc) cst1 = cnew; else cst0 = cnew;
        hv[cc] = og * fast_tanh(cnew);
      }
      f16x2 pk; pk[0] = (f16)hv[0]; pk[1] = (f16)hv[1];
      unsigned* dst = (unsigned*)(h1base + (size_t)(s + 1) * 32768 +
                                  (size_t)wg * 1024 + rb * 32 + hp * 4);
      st_sc1_u32(dst, __builtin_bit_cast(unsigned, pk));
    }
    if (s >= 1 && tid >= 256) {          // L1 -> H2S slot s
      const int t2 = tid - 256;
      const int rb = t2 >> 3, hp = t2 & 7;
      const float* gr = g1 + rb * 68;
      float hv[2];
#pragma unroll
      for (int cc = 0; cc < 2; ++cc) {
        const int c = 2 * hp + cc;
        const float pi = gr[c]      + gr[2176 + c]      + bias1[c];
        const float pf = gr[16 + c] + gr[2176 + 16 + c] + bias1[16 + c];
        const float pg = gr[32 + c] + gr[2176 + 32 + c] + bias1[32 + c];
        const float po = gr[48 + c] + gr[2176 + 48 + c] + bias1[48 + c];
        const float ig = fast_sig(pi), fg = fast_sig(pf);
        const float gg = fast_tanh(pg), og = fast_sig(po);
        const float cprev = cc ? dst1 : dst0;
        const float cnew = fg * cprev + ig * gg;
        if (cc) dst1 = cnew; else dst0 = cnew;
        hv[cc] = og * fast_tanh(cnew);
      }
      f16x2 pk; pk[0] = (f16)hv[0]; pk[1] = (f16)hv[1];
      unsigned* dst = (unsigned*)(h2base + (size_t)s * 32768 +
                                  (size_t)wg * 1024 + rb * 32 + hp * 4);
      st_sc1_u32(dst, __builtin_bit_cast(unsigned, pk));
    }

    // ---- publish: per-wave drain, barrier (=> all drained), one flag ----
    asm volatile("s_waitcnt vmcnt(0)" ::: "memory");
    __syncthreads();
    if (tid == 0) st_sc1_u32(flags + wg * 16, (unsigned)(s + 1));
    __builtin_amdgcn_sched_barrier(0);
  }
}

// fused FC1+FC2 reading block layout (R6-identical): rows bt = b*1024 + t.
__global__ __launch_bounds__(256) void fc_fused(const char* __restrict__ ws_h2,
                                                const float* __restrict__ fcW,
                                                const float* __restrict__ fcb,
                                                const float* __restrict__ fc2W,
                                                const float* __restrict__ fc2b,
                                                float* __restrict__ out) {
  __shared__ float hT[64][36];
  __shared__ float wT[128][36];
  __shared__ float oL[64][136];
  const int bt0 = blockIdx.x * 64;
  const int b   = bt0 >> 10;
  const int t0  = bt0 & 1023;
  const int t = threadIdx.x;
  const int c4 = (t & 31) * 4;
  const int rowg = t >> 5;
  float acc[8][4];
#pragma unroll
  for (int r = 0; r < 8; ++r)
#pragma unroll
    for (int j = 0; j < 4; ++j) acc[r][j] = 0.f;

  for (int kc = 0; kc < 16; ++kc) {
    {
      const int r = t >> 2, q = t & 3;
      const int c0 = kc * 32 + q * 8;
      const f16x8 v = *(const f16x8*)(ws_h2 + (size_t)(t0 + r + 1) * 32768 +
                                      (size_t)(c0 >> 4) * 1024 + b * 32 + (c0 & 15) * 2);
#pragma unroll
      for (int j = 0; j < 8; ++j) hT[r][q * 8 + j] = (float)v[j];
    }
#pragma unroll
    for (int u = t; u < 1024; u += 256) {
      const int cc = u >> 3, k4 = u & 7;
      *(float4*)&wT[cc][k4 * 4] = *(const float4*)(fcW + (size_t)cc * 512 + kc * 32 + k4 * 4);
    }
    __syncthreads();
#pragma unroll
    for (int k4 = 0; k4 < 8; ++k4) {
      float4 w0 = *(float4*)&wT[c4 + 0][k4 * 4];
      float4 w1 = *(float4*)&wT[c4 + 1][k4 * 4];
      float4 w2 = *(float4*)&wT[c4 + 2][k4 * 4];
      float4 w3 = *(float4*)&wT[c4 + 3][k4 * 4];
#pragma unroll
      for (int rr = 0; rr < 8; ++rr) {
        float4 h = *(float4*)&hT[rowg * 8 + rr][k4 * 4];
        acc[rr][0] += h.x * w0.x + h.y * w0.y + h.z * w0.z + h.w * w0.w;
        acc[rr][1] += h.x * w1.x + h.y * w1.y + h.z * w1.z + h.w * w1.w;
        acc[rr][2] += h.x * w2.x + h.y * w2.y + h.z * w2.z + h.w * w2.w;
        acc[rr][3] += h.x * w3.x + h.y * w3.y + h.z * w3.z + h.w * w3.w;
      }
    }
    __syncthreads();
  }
#pragma unroll
  for (int rr = 0; rr < 8; ++rr)
#pragma unroll
    for (int j = 0; j < 4; ++j)
      oL[rowg * 8 + rr][c4 + j] = acc[rr][j] + fcb[c4 + j];
  __syncthreads();
  float a2[8][4];
#pragma unroll
  for (int r = 0; r < 8; ++r)
#pragma unroll
    for (int j = 0; j < 4; ++j) a2[r][j] = 0.f;
#pragma unroll
  for (int k4 = 0; k4 < 32; ++k4) {
    float4 w0 = *(const float4*)(fc2W + (size_t)(c4 + 0) * 128 + k4 * 4);
    float4 w1 = *(const float4*)(fc2W + (size_t)(c4 + 1) * 128 + k4 * 4);
    float4 w2 = *(const float4*)(fc2W + (size_t)(c4 + 2) * 128 + k4 * 4);
    float4 w3 = *(const float4*)(fc2W + (size_t)(c4 + 3) * 128 + k4 * 4);
#pragma unroll
    for (int rr = 0; rr < 8; ++rr) {
      float4 h = *(float4*)&oL[rowg * 8 + rr][k4 * 4];
      a2[rr][0] += h.x * w0.x + h.y * w0.y + h.z * w0.z + h.w * w0.w;
      a2[rr][1] += h.x * w1.x + h.y * w1.y + h.z * w1.z + h.w * w1.w;
      a2[rr][2] += h.x * w2.x + h.y * w2.y + h.z * w2.z + h.w * w2.w;
      a2[rr][3] += h.x * w3.x + h.y * w3.y + h.z * w3.z + h.w * w3.w;
    }
  }
#pragma unroll
  for (int rr = 0; rr < 8; ++rr) {
    const int r = bt0 + rowg * 8 + rr;
#pragma unroll
    for (int j = 0; j < 4; ++j)
      out[(size_t)r * 128 + c4 + j] = a2[rr][j] + fc2b[c4 + j];
  }
}

extern "C" void kernel_launch(void* const* d_in, const int* in_sizes, int n_in,
                              void* d_out, int out_size, void* d_ws, size_t ws_size,
                              hipStream_t stream) {
  (void)in_sizes; (void)n_in; (void)out_size; (void)ws_size;
  const float* x    = (const float*)d_in[0];
  const float* Wih0 = (const float*)d_in[1];
  const float* Whh0 = (const float*)d_in[2];
  const float* bih0 = (const float*)d_in[3];
  const float* bhh0 = (const float*)d_in[4];
  const float* Wih1 = (const float*)d_in[5];
  const float* Whh1 = (const float*)d_in[6];
  const float* bih1 = (const float*)d_in[7];
  const float* bhh1 = (const float*)d_in[8];
  const float* fcW  = (const float*)d_in[9];
  const float* fcb  = (const float*)d_in[10];
  const float* fc2W = (const float*)d_in[11];
  const float* fc2b = (const float*)d_in[12];

  char* ws = (char*)d_ws;
  f16* xT = (f16*)(ws + OFF_XT);
  float* out = (float*)d_out;

  // per-call init: flags + zero slot-0 of both exchange arrays (h[-1] = 0)
  (void)hipMemsetAsync(ws + OFF_FLAGS, 0, 2048, stream);
  (void)hipMemsetAsync(ws + OFF_H1S, 0, 32768, stream);
  (void)hipMemsetAsync(ws + OFF_H2S, 0, 32768, stream);

  prep_xT<<<4096, 256, 0, stream>>>(x, xT);
  lstm_persist<<<NWG, THR, 0, stream>>>(Wih0, Whh0, bih0, bhh0,
                                        Wih1, Whh1, bih1, bhh1, ws);
  fc_fused<<<512, 256, 0, stream>>>(ws + OFF_H2S, fcW, fcb, fc2W, fc2b, out);
}

// Round 11
// 3793.924 us; speedup vs baseline: 2.8868x; 1.1442x over previous
//
#include <hip/hip_runtime.h>
#include <math.h>

typedef _Float16 f16;
typedef _Float16 f16x8 __attribute__((ext_vector_type(8)));
typedef _Float16 f16x4 __attribute__((ext_vector_type(4)));
typedef _Float16 f16x2 __attribute__((ext_vector_type(2)));
typedef float f32x16 __attribute__((ext_vector_type(16)));
typedef int i32x4 __attribute__((ext_vector_type(4)));

#define B_ 32
#define T_ 1024
#define I_ 128
#define H_ 512

#define NWG 64          // 32 L0-WGs + 32 L1-WGs (one-way pipeline)
#define THR 512

// ---- workspace layout (bytes) ----
#define OFF_FLAGS 0UL                 // flags0: 32 x 64B; flags1 at +2048; total 4096
#define OFF_H1S   4096UL              // [1025][32768] slot k = h1[t=k-1]; [wg][32b x 16c f16]
#define OFF_H2S   33591296UL          // [1025][32768] slot k = h2[t=k-1]
#define OFF_XT    67178496UL          // f16 [1024][32][128] = 8,388,608
// total 75,567,104 B

__device__ inline f32x16 mfma32(f16x8 a, f16x8 b, f32x16 c) {
  return __builtin_amdgcn_mfma_f32_32x32x16_f16(a, b, c, 0, 0, 0);
}
__device__ inline float fast_sig(float x) { return 1.f / (1.f + __expf(-x)); }
__device__ inline float fast_tanh(float x) {
  float e = __expf(-2.f * fabsf(x));
  float t = (1.f - e) / (1.f + e);
  return x < 0.f ? -t : t;
}

// sc1 = device-coherent (MALL) protocol primitives — R2/R6-proven
__device__ inline unsigned ld_sc1_u32(const unsigned* p) {
  unsigned r;
  asm volatile("global_load_dword %0, %1, off sc1\n\ts_waitcnt vmcnt(0)"
               : "=v"(r) : "v"(p) : "memory");
  return r;
}
__device__ inline void st_sc1_u32(unsigned* p, unsigned v) {
  asm volatile("global_store_dword %0, %1, off sc1" :: "v"(p), "v"(v) : "memory");
}

// LDS XOR-swizzle (R2/R6/R10-proven)
__device__ inline int swz_h(int b, int kbyte) { return b * 1024 + (kbyte ^ ((b & 7) << 4)); }
__device__ inline int swz_x(int b, int kbyte) { return b * 256  + (kbyte ^ ((b & 7) << 4)); }

// x[b][t][i] f32 -> xT[t][b][i] f16
__global__ __launch_bounds__(256) void prep_xT(const float* __restrict__ x, f16* __restrict__ xT) {
  const int idx = blockIdx.x * 256 + threadIdx.x;
  const int n4 = B_ * T_ * I_ / 4;
  if (idx < n4) {
    const int i4 = idx * 4;
    const int i  = i4 & (I_ - 1);
    const int tt = (i4 >> 7) & (T_ - 1);
    const int b  = i4 >> 17;
    float4 v = *(const float4*)(x + i4);
    f16x4 o;
    o[0] = (f16)v.x; o[1] = (f16)v.y; o[2] = (f16)v.z; o[3] = (f16)v.w;
    *(f16x4*)(xT + ((size_t)tt * B_ + b) * I_ + i) = o;
  }
}

// Role-split persistent 2-layer LSTM. WGs 0-31: layer 0 (h1 chain, the critical loop).
// WGs 32-63: layer 1, self-paced one step behind (consumes write-once h1 slots).
// Inner MFMA/pointwise/staging/protocol code identical to round 10.
__global__ __launch_bounds__(THR, 1) void lstm_persist(
    const float* __restrict__ Wih0, const float* __restrict__ Whh0,
    const float* __restrict__ bih0, const float* __restrict__ bhh0,
    const float* __restrict__ Wih1, const float* __restrict__ Whh1,
    const float* __restrict__ bih1, const float* __restrict__ bhh1,
    char* ws) {
  __shared__ i32x4 h1l4[2048];          // 32KB  h1 tile (swizzled)
  __shared__ i32x4 h2l4[2048];          // 32KB  h2 tile (L1 role)
  __shared__ i32x4 xl4[512];            // 8KB   x tile (L0 role)
  __shared__ float gbuf[2 * 32 * 68];   // gate partials [kq][32b][64c pad 68]
  __shared__ float biasl[64];

  const int tid  = threadIdx.x;
  const int wgid = blockIdx.x;
  const int role = wgid >> 5;           // 0 = L0, 1 = L1
  const int gid  = wgid & 31;
  const int lane = tid & 63;
  const int wv   = tid >> 6;
  const int nt   = wv & 1;              // 32-col N-tile (MFMA waves 0-3)
  const int kq   = (wv >> 1) & 1;       // K-half
  const int bl   = lane & 31;
  const int kg   = lane >> 5;

  unsigned* flags0 = (unsigned*)(ws + OFF_FLAGS);
  unsigned* flags1 = (unsigned*)(ws + OFF_FLAGS + 2048);
  const char* h1base = ws + OFF_H1S;
  const char* h2base = ws + OFF_H2S;

  if (tid < 64) {
    const int g = tid >> 4, hc = tid & 15;
    const int row = g * 512 + gid * 16 + hc;
    biasl[tid] = role ? (bih1[row] + bhh1[row]) : (bih0[row] + bhh0[row]);
  }

  // ---- weight preload into VGPRs (R10-identical fragments; MFMA waves only) ----
  const int n    = nt * 32 + bl;
  const int wrow = (n >> 4) * 512 + gid * 16 + (n & 15);
  f16x8 wreg[32];
  if (role == 0) {
    if (wv < 4) {
#pragma unroll
      for (int ks = 0; ks < 20; ++ks) {
        const int k = kq * 320 + ks * 16 + kg * 8;
        const float* src = (k < I_) ? (Wih0 + (size_t)wrow * I_ + k)
                                    : (Whh0 + (size_t)wrow * H_ + (k - I_));
        float4 v0 = *(const float4*)(src);
        float4 v1 = *(const float4*)(src + 4);
        f16x8 h;
        h[0] = (f16)v0.x; h[1] = (f16)v0.y; h[2] = (f16)v0.z; h[3] = (f16)v0.w;
        h[4] = (f16)v1.x; h[5] = (f16)v1.y; h[6] = (f16)v1.z; h[7] = (f16)v1.w;
        wreg[ks] = h;
      }
    }
  } else {
    if (wv < 4) {
#pragma unroll
      for (int ks = 0; ks < 32; ++ks) {
        const int k = kq * 512 + ks * 16 + kg * 8;
        const float* src = (k < H_) ? (Wih1 + (size_t)wrow * H_ + k)
                                    : (Whh1 + (size_t)wrow * H_ + (k - H_));
        float4 v0 = *(const float4*)(src);
        float4 v1 = *(const float4*)(src + 4);
        f16x8 h;
        h[0] = (f16)v0.x; h[1] = (f16)v0.y; h[2] = (f16)v0.z; h[3] = (f16)v0.w;
        h[4] = (f16)v1.x; h[5] = (f16)v1.y; h[6] = (f16)v1.z; h[7] = (f16)v1.w;
        wreg[ks] = h;
      }
    }
  }

  float cst0 = 0.f, cst1 = 0.f;         // cell state for pointwise threads (tid<256)
  const char* h1c = (const char*)h1l4;
  const char* h2c = (const char*)h2l4;
  const char* xc  = (const char*)xl4;

  __syncthreads();

  if (role == 0) {
    // ================= layer 0 — the critical h1 loop =================
    for (int s = 0; s < T_; ++s) {
      i32x4 xv = ((const i32x4*)(ws + OFF_XT))[(size_t)s * 512 + tid];  // prefetch

      if (s >= 1) {                      // gate: all flags0 >= s (h1[s-1] in slot s)
        if (tid < 64) {
          const unsigned tgt = (unsigned)s;
          const unsigned* fp = flags0 + (tid < 32 ? tid : 0) * 16;
          const bool active = tid < 32;
          for (;;) {
            unsigned v = ld_sc1_u32(fp);
            if (!active) v = tgt;
            if (__all((int)(v >= tgt))) break;
            __builtin_amdgcn_s_sleep(1);
          }
        }
        __syncthreads();
      }

      // stage h1[s-1] (slot s) + x[s] -> swizzled LDS (R10-identical)
      {
        const i32x4* src = (const i32x4*)(h1base + (size_t)s * 32768);
#pragma unroll
        for (int r = 0; r < 4; ++r) {
          const int u = r * 512 + tid;
          i32x4 v = src[u];
          const int wgs = u >> 6, b = (u >> 1) & 31, half = u & 1;
          *(i32x4*)((char*)h1l4 + swz_h(b, wgs * 32 + half * 16)) = v;
        }
      }
      *(i32x4*)((char*)xl4 + swz_x(tid >> 4, (tid & 15) * 16)) = xv;
      __syncthreads();

      // MFMA (waves 0-3; R10 L0 body verbatim)
      if (wv < 4) {
        f32x16 acc = {};
        if (kq == 0) {
#pragma unroll
          for (int ks = 0; ks < 8; ++ks) {
            f16x8 a = *(const f16x8*)(xc + swz_x(bl, (ks * 16 + kg * 8) * 2));
            acc = mfma32(a, wreg[ks], acc);
          }
#pragma unroll
          for (int ks = 8; ks < 20; ++ks) {
            f16x8 a = *(const f16x8*)(h1c + swz_h(bl, (ks * 16 + kg * 8 - I_) * 2));
            acc = mfma32(a, wreg[ks], acc);
          }
        } else {
#pragma unroll
          for (int ks = 0; ks < 20; ++ks) {
            f16x8 a = *(const f16x8*)(h1c + swz_h(bl, (192 + ks * 16 + kg * 8) * 2));
            acc = mfma32(a, wreg[ks], acc);
          }
        }
        const int cb = nt * 32 + bl;
#pragma unroll
        for (int r = 0; r < 16; ++r) {
          const int row = (r & 3) + 8 * (r >> 2) + 4 * kg;   // m74-verified C/D layout
          gbuf[kq * 2176 + row * 68 + cb] = acc[r];
        }
      }
      __syncthreads();

      // pointwise + block-contiguous sc1 store (R10 L0 body verbatim)
      if (tid < 256) {
        const int rb = tid >> 3, hp = tid & 7;
        const float* gr = gbuf + rb * 68;
        float hv[2];
#pragma unroll
        for (int cc = 0; cc < 2; ++cc) {
          const int c = 2 * hp + cc;
          const float pi = gr[c]      + gr[2176 + c]      + biasl[c];
          const float pf = gr[16 + c] + gr[2176 + 16 + c] + biasl[16 + c];
          const float pg = gr[32 + c] + gr[2176 + 32 + c] + biasl[32 + c];
          const float po = gr[48 + c] + gr[2176 + 48 + c] + biasl[48 + c];
          const float ig = fast_sig(pi), fg = fast_sig(pf);
          const float gg = fast_tanh(pg), og = fast_sig(po);
          const float cprev = cc ? cst1 : cst0;
          const float cnew = fg * cprev + ig * gg;
          if (cc) cst1 = cnew; else cst0 = cnew;
          hv[cc] = og * fast_tanh(cnew);
        }
        f16x2 pk; pk[0] = (f16)hv[0]; pk[1] = (f16)hv[1];
        unsigned* dst = (unsigned*)(h1base + (size_t)(s + 1) * 32768 +
                                    (size_t)gid * 1024 + rb * 32 + hp * 4);
        st_sc1_u32(dst, __builtin_bit_cast(unsigned, pk));
      }

      asm volatile("s_waitcnt vmcnt(0)" ::: "memory");
      __syncthreads();
      if (tid == 0) st_sc1_u32(flags0 + gid * 16, (unsigned)(s + 1));
      __builtin_amdgcn_sched_barrier(0);
    }
  } else {
    // ================= layer 1 — self-paced, one step behind =================
    for (int t = 0; t < T_; ++t) {
      // gate: flags0 >= t+1 (h1[t] in slot t+1) AND flags1 >= t (h2[t-1] in slot t)
      if (tid < 64) {
        for (;;) {
          unsigned v, tgt;
          if (lane < 32) { v = ld_sc1_u32(flags0 + lane * 16); tgt = (unsigned)(t + 1); }
          else           { v = ld_sc1_u32(flags1 + (lane - 32) * 16); tgt = (unsigned)t; }
          if (__all((int)(v >= tgt))) break;
          __builtin_amdgcn_s_sleep(1);
        }
      }
      __syncthreads();

      // stage h1[t] (slot t+1) + h2[t-1] (slot t) -> swizzled LDS
      {
        const i32x4* src = (const i32x4*)(h1base + (size_t)(t + 1) * 32768);
#pragma unroll
        for (int r = 0; r < 4; ++r) {
          const int u = r * 512 + tid;
          i32x4 v = src[u];
          const int wgs = u >> 6, b = (u >> 1) & 31, half = u & 1;
          *(i32x4*)((char*)h1l4 + swz_h(b, wgs * 32 + half * 16)) = v;
        }
      }
      {
        const i32x4* src = (const i32x4*)(h2base + (size_t)t * 32768);
#pragma unroll
        for (int r = 0; r < 4; ++r) {
          const int u = r * 512 + tid;
          i32x4 v = src[u];
          const int wgs = u >> 6, b = (u >> 1) & 31, half = u & 1;
          *(i32x4*)((char*)h2l4 + swz_h(b, wgs * 32 + half * 16)) = v;
        }
      }
      __syncthreads();

      // MFMA (waves 0-3; R10 L1 body verbatim)
      if (wv < 4) {
        f32x16 acc = {};
        if (kq == 0) {
#pragma unroll
          for (int ks = 0; ks < 32; ++ks) {
            f16x8 a = *(const f16x8*)(h1c + swz_h(bl, (ks * 16 + kg * 8) * 2));
            acc = mfma32(a, wreg[ks], acc);
          }
        } else {
#pragma unroll
          for (int ks = 0; ks < 32; ++ks) {
            f16x8 a = *(const f16x8*)(h2c + swz_h(bl, (ks * 16 + kg * 8) * 2));
            acc = mfma32(a, wreg[ks], acc);
          }
        }
        const int cb = nt * 32 + bl;
#pragma unroll
        for (int r = 0; r < 16; ++r) {
          const int row = (r & 3) + 8 * (r >> 2) + 4 * kg;
          gbuf[kq * 2176 + row * 68 + cb] = acc[r];
        }
      }
      __syncthreads();

      // pointwise + h2 store (R10 L1 body)
      if (tid < 256) {
        const int rb = tid >> 3, hp = tid & 7;
        const float* gr = gbuf + rb * 68;
        float hv[2];
#pragma unroll
        for (int cc = 0; cc < 2; ++cc) {
          const int c = 2 * hp + cc;
          const float pi = gr[c]      + gr[2176 + c]      + biasl[c];
          const float pf = gr[16 + c] + gr[2176 + 16 + c] + biasl[16 + c];
          const float pg = gr[32 + c] + gr[2176 + 32 + c] + biasl[32 + c];
          const float po = gr[48 + c] + gr[2176 + 48 + c] + biasl[48 + c];
          const float ig = fast_sig(pi), fg = fast_sig(pf);
          const float gg = fast_tanh(pg), og = fast_sig(po);
          const float cprev = cc ? cst1 : cst0;
          const float cnew = fg * cprev + ig * gg;
          if (cc) cst1 = cnew; else cst0 = cnew;
          hv[cc] = og * fast_tanh(cnew);
        }
        f16x2 pk; pk[0] = (f16)hv[0]; pk[1] = (f16)hv[1];
        unsigned* dst = (unsigned*)(h2base + (size_t)(t + 1) * 32768 +
                                    (size_t)gid * 1024 + rb * 32 + hp * 4);
        st_sc1_u32(dst, __builtin_bit_cast(unsigned, pk));
      }

      asm volatile("s_waitcnt vmcnt(0)" ::: "memory");
      __syncthreads();
      if (tid == 0) st_sc1_u32(flags1 + gid * 16, (unsigned)(t + 1));
      __builtin_amdgcn_sched_barrier(0);
    }
  }
}

// fused FC1+FC2 reading block layout (R6-identical): rows bt = b*1024 + t.
__global__ __launch_bounds__(256) void fc_fused(const char* __restrict__ ws_h2,
                                                const float* __restrict__ fcW,
                                                const float* __restrict__ fcb,
                                                const float* __restrict__ fc2W,
                                                const float* __restrict__ fc2b,
                                                float* __restrict__ out) {
  __shared__ float hT[64][36];
  __shared__ float wT[128][36];
  __shared__ float oL[64][136];
  const int bt0 = blockIdx.x * 64;
  const int b   = bt0 >> 10;
  const int t0  = bt0 & 1023;
  const int t = threadIdx.x;
  const int c4 = (t & 31) * 4;
  const int rowg = t >> 5;
  float acc[8][4];
#pragma unroll
  for (int r = 0; r < 8; ++r)
#pragma unroll
    for (int j = 0; j < 4; ++j) acc[r][j] = 0.f;

  for (int kc = 0; kc < 16; ++kc) {
    {
      const int r = t >> 2, q = t & 3;
      const int c0 = kc * 32 + q * 8;
      const f16x8 v = *(const f16x8*)(ws_h2 + (size_t)(t0 + r + 1) * 32768 +
                                      (size_t)(c0 >> 4) * 1024 + b * 32 + (c0 & 15) * 2);
#pragma unroll
      for (int j = 0; j < 8; ++j) hT[r][q * 8 + j] = (float)v[j];
    }
#pragma unroll
    for (int u = t; u < 1024; u += 256) {
      const int cc = u >> 3, k4 = u & 7;
      *(float4*)&wT[cc][k4 * 4] = *(const float4*)(fcW + (size_t)cc * 512 + kc * 32 + k4 * 4);
    }
    __syncthreads();
#pragma unroll
    for (int k4 = 0; k4 < 8; ++k4) {
      float4 w0 = *(float4*)&wT[c4 + 0][k4 * 4];
      float4 w1 = *(float4*)&wT[c4 + 1][k4 * 4];
      float4 w2 = *(float4*)&wT[c4 + 2][k4 * 4];
      float4 w3 = *(float4*)&wT[c4 + 3][k4 * 4];
#pragma unroll
      for (int rr = 0; rr < 8; ++rr) {
        float4 h = *(float4*)&hT[rowg * 8 + rr][k4 * 4];
        acc[rr][0] += h.x * w0.x + h.y * w0.y + h.z * w0.z + h.w * w0.w;
        acc[rr][1] += h.x * w1.x + h.y * w1.y + h.z * w1.z + h.w * w1.w;
        acc[rr][2] += h.x * w2.x + h.y * w2.y + h.z * w2.z + h.w * w2.w;
        acc[rr][3] += h.x * w3.x + h.y * w3.y + h.z * w3.z + h.w * w3.w;
      }
    }
    __syncthreads();
  }
#pragma unroll
  for (int rr = 0; rr < 8; ++rr)
#pragma unroll
    for (int j = 0; j < 4; ++j)
      oL[rowg * 8 + rr][c4 + j] = acc[rr][j] + fcb[c4 + j];
  __syncthreads();
  float a2[8][4];
#pragma unroll
  for (int r = 0; r < 8; ++r)
#pragma unroll
    for (int j = 0; j < 4; ++j) a2[r][j] = 0.f;
#pragma unroll
  for (int k4 = 0; k4 < 32; ++k4) {
    float4 w0 = *(const float4*)(fc2W + (size_t)(c4 + 0) * 128 + k4 * 4);
    float4 w1 = *(const float4*)(fc2W + (size_t)(c4 + 1) * 128 + k4 * 4);
    float4 w2 = *(const float4*)(fc2W + (size_t)(c4 + 2) * 128 + k4 * 4);
    float4 w3 = *(const float4*)(fc2W + (size_t)(c4 + 3) * 128 + k4 * 4);
#pragma unroll
    for (int rr = 0; rr < 8; ++rr) {
      float4 h = *(float4*)&oL[rowg * 8 + rr][k4 * 4];
      a2[rr][0] += h.x * w0.x + h.y * w0.y + h.z * w0.z + h.w * w0.w;
      a2[rr][1] += h.x * w1.x + h.y * w1.y + h.z * w1.z + h.w * w1.w;
      a2[rr][2] += h.x * w2.x + h.y * w2.y + h.z * w2.z + h.w * w2.w;
      a2[rr][3] += h.x * w3.x + h.y * w3.y + h.z * w3.z + h.w * w3.w;
    }
  }
#pragma unroll
  for (int rr = 0; rr < 8; ++rr) {
    const int r = bt0 + rowg * 8 + rr;
#pragma unroll
    for (int j = 0; j < 4; ++j)
      out[(size_t)r * 128 + c4 + j] = a2[rr][j] + fc2b[c4 + j];
  }
}

extern "C" void kernel_launch(void* const* d_in, const int* in_sizes, int n_in,
                              void* d_out, int out_size, void* d_ws, size_t ws_size,
                              hipStream_t stream) {
  (void)in_sizes; (void)n_in; (void)out_size; (void)ws_size;
  const float* x    = (const float*)d_in[0];
  const float* Wih0 = (const float*)d_in[1];
  const float* Whh0 = (const float*)d_in[2];
  const float* bih0 = (const float*)d_in[3];
  const float* bhh0 = (const float*)d_in[4];
  const float* Wih1 = (const float*)d_in[5];
  const float* Whh1 = (const float*)d_in[6];
  const float* bih1 = (const float*)d_in[7];
  const float* bhh1 = (const float*)d_in[8];
  const float* fcW  = (const float*)d_in[9];
  const float* fcb  = (const float*)d_in[10];
  const float* fc2W = (const float*)d_in[11];
  const float* fc2b = (const float*)d_in[12];

  char* ws = (char*)d_ws;
  f16* xT = (f16*)(ws + OFF_XT);
  float* out = (float*)d_out;

  // per-call init: both flag arrays + zero slot-0 of both exchange arrays (h[-1] = 0)
  (void)hipMemsetAsync(ws + OFF_FLAGS, 0, 4096, stream);
  (void)hipMemsetAsync(ws + OFF_H1S, 0, 32768, stream);
  (void)hipMemsetAsync(ws + OFF_H2S, 0, 32768, stream);

  prep_xT<<<4096, 256, 0, stream>>>(x, xT);
  lstm_persist<<<NWG, THR, 0, stream>>>(Wih0, Whh0, bih0, bhh0,
                                        Wih1, Whh1, bih1, bhh1, ws);
  fc_fused<<<512, 256, 0, stream>>>(ws + OFF_H2S, fcW, fcb, fc2W, fc2b, out);
}